// Round 8
// baseline (261.427 us; speedup 1.0000x reference)
//
#include <hip/hip_runtime.h>

typedef unsigned short u16;
typedef unsigned int u32;
typedef __bf16 bf16x8 __attribute__((ext_vector_type(8)));
typedef __bf16 bf16x4 __attribute__((ext_vector_type(4)));
typedef float floatx4 __attribute__((ext_vector_type(4)));

#define BB 2
#define TT 2048
#define DD 1024
#define HH 16
#define DKK 64
#define ACT (BB * TT * DD)      // 4194304 elements
#define WTE (DD * DD)           // 1048576 elements

__device__ inline u16 f2bf(float f) {
    union { float f; u32 u; } c; c.f = f;
    u32 r = (c.u + 0x7fffu + ((c.u >> 16) & 1u)) >> 16;
    return (u16)r;
}
__device__ inline u32 pack2bf(float a, float b) {
    return (u32)f2bf(a) | ((u32)f2bf(b) << 16);
}

// async global->LDS, 16B per lane; LDS dest = wave-uniform base + lane*16
typedef __attribute__((address_space(1))) const u32 gas_u32;
typedef __attribute__((address_space(3))) u32 las_u32;
__device__ __forceinline__ void gl2lds16(const u16* g, u16* l) {
    __builtin_amdgcn_global_load_lds((gas_u32*)g, (las_u32*)l, 16, 0, 0);
}

// ---------------- fp32 -> bf16 convert pass ----------------
struct CvtArgs { const float* src[7]; u16* dst[7]; };
__global__ __launch_bounds__(256) void convert_bf16(CvtArgs a) {
    int bid = blockIdx.x, t, local;
    if (bid < 768) { t = bid >> 8; local = bid & 255; }
    else { int r = bid - 768; t = 3 + (r >> 6); local = r & 63; }
    const float* s = a.src[t];
    u16* d = a.dst[t];
    const int base = local * 16384;
    for (int i = 0; i < 8; i++) {
        const int idx = base + i * 2048 + threadIdx.x * 8;
        float4 x0 = *(const float4*)(s + idx);
        float4 x1 = *(const float4*)(s + idx + 4);
        uint4 p;
        p.x = pack2bf(x0.x, x0.y); p.y = pack2bf(x0.z, x0.w);
        p.z = pack2bf(x1.x, x1.y); p.w = pack2bf(x1.z, x1.w);
        *(uint4*)(d + idx) = p;
    }
}

// ---------------- fused QKV projection (m97-style staging) ----------------
// z=0: Q*0.125 -> ws[b][h][t][dk]   z=1: K -> same layout
// z=2: V -> ws[b][h][dk][t_perm], keys permuted within 64-blocks to match
//      the attention kernel's packed-P column order (j = c + key16*4).
__global__ __launch_bounds__(256) void qkv_gemm(
    const u16* __restrict__ Qc, const u16* __restrict__ Kc,
    const u16* __restrict__ Vc,
    const u16* __restrict__ Wqc, const u16* __restrict__ Wkc,
    const u16* __restrict__ Wvc,
    const float* __restrict__ bq, const float* __restrict__ bk,
    const float* __restrict__ bv,
    u16* __restrict__ ws)
{
    __shared__ __align__(16) u16 As[128 * 32];
    __shared__ __align__(16) u16 Bs[128 * 32];
    const int z = blockIdx.z;
    const u16* A = (z == 0) ? Qc : (z == 1) ? Kc : Vc;
    const u16* W = (z == 0) ? Wqc : (z == 1) ? Wkc : Wvc;
    const float* bias = (z == 0) ? bq : (z == 1) ? bk : bv;
    u16* out = ws + (size_t)z * (size_t)BB * HH * TT * DKK;

    const int tid  = threadIdx.x;
    const int wave = tid >> 6, lane = tid & 63;
    const int quad = lane >> 4, l16 = lane & 15;
    const int wm = wave & 1, wn = wave >> 1;
    const int m0 = blockIdx.y * 128, n0 = blockIdx.x * 128;
    const int K = DD;

    const int lrow = lane >> 2, lcol = (lane & 3) * 8;
    const u16* Ag0 = A + (size_t)(m0 + wave * 16 + lrow) * K + lcol;
    const u16* Ag1 = A + (size_t)(m0 + 64 + wave * 16 + lrow) * K + lcol;
    const u16* Wg0 = W + (size_t)(n0 + wave * 16 + lrow) * K + lcol;
    const u16* Wg1 = W + (size_t)(n0 + 64 + wave * 16 + lrow) * K + lcol;
    u16* AsD0 = &As[(wave * 16) * 32];
    u16* AsD1 = &As[(64 + wave * 16) * 32];
    u16* BsD0 = &Bs[(wave * 16) * 32];
    u16* BsD1 = &Bs[(64 + wave * 16) * 32];

    floatx4 acc[4][4];
    for (int i = 0; i < 4; i++)
        for (int j = 0; j < 4; j++)
            acc[i][j] = floatx4{0.f, 0.f, 0.f, 0.f};

    for (int k0 = 0; k0 < K; k0 += 32) {
        __syncthreads();
        gl2lds16(Ag0 + k0, AsD0);
        gl2lds16(Ag1 + k0, AsD1);
        gl2lds16(Wg0 + k0, BsD0);
        gl2lds16(Wg1 + k0, BsD1);
        __syncthreads();

        bf16x8 af[4], bfr[4];
        for (int mi = 0; mi < 4; mi++)
            af[mi] = *(const bf16x8*)&As[(wm * 64 + mi * 16 + l16) * 32 + quad * 8];
        for (int ni = 0; ni < 4; ni++)
            bfr[ni] = *(const bf16x8*)&Bs[(wn * 64 + ni * 16 + l16) * 32 + quad * 8];
        for (int mi = 0; mi < 4; mi++)
            for (int ni = 0; ni < 4; ni++)
                acc[mi][ni] = __builtin_amdgcn_mfma_f32_16x16x32_bf16(
                    af[mi], bfr[ni], acc[mi][ni], 0, 0, 0);
    }

    for (int ni = 0; ni < 4; ni++) {
        const int n = n0 + wn * 64 + ni * 16 + l16;
        const float bv2 = bias[n];
        for (int mi = 0; mi < 4; mi++) {
            for (int vv = 0; vv < 4; vv++) {
                const int m = m0 + wm * 64 + mi * 16 + quad * 4 + vv;
                float val = acc[mi][ni][vv] + bv2;
                if (z == 0) val *= 0.125f;   // fold 1/sqrt(DK), exact pow2
                const int b = m >> 11, t = m & 2047, h = n >> 6, dk = n & 63;
                if (z == 2) {
                    // key permutation within 64-blocks: j = c + key16*4
                    const int tp = (t & ~63) | ((t >> 4) & 3) | ((t & 15) << 2);
                    out[(((size_t)(b * HH + h)) * DKK + dk) * TT + tp] = f2bf(val);
                } else {
                    out[(((size_t)(b * HH + h)) * TT + t) * DKK + dk] = f2bf(val);
                }
            }
        }
    }
}

// ---------------- output projection (m97-style staging) ----------------
__global__ __launch_bounds__(256) void out_gemm(
    const u16* __restrict__ Av, const u16* __restrict__ Wv,
    const float* __restrict__ bias, float* __restrict__ outv)
{
    __shared__ __align__(16) u16 As[128 * 32];
    __shared__ __align__(16) u16 Bs[128 * 32];
    const int tid  = threadIdx.x;
    const int wave = tid >> 6, lane = tid & 63;
    const int quad = lane >> 4, l16 = lane & 15;
    const int wm = wave & 1, wn = wave >> 1;
    const int m0 = blockIdx.y * 128, n0 = blockIdx.x * 128;
    const int K = DD, N = DD;

    const int lrow = lane >> 2, lcol = (lane & 3) * 8;
    const u16* Ag0 = Av + (size_t)(m0 + wave * 16 + lrow) * K + lcol;
    const u16* Ag1 = Av + (size_t)(m0 + 64 + wave * 16 + lrow) * K + lcol;
    const u16* Wg0 = Wv + (size_t)(n0 + wave * 16 + lrow) * K + lcol;
    const u16* Wg1 = Wv + (size_t)(n0 + 64 + wave * 16 + lrow) * K + lcol;
    u16* AsD0 = &As[(wave * 16) * 32];
    u16* AsD1 = &As[(64 + wave * 16) * 32];
    u16* BsD0 = &Bs[(wave * 16) * 32];
    u16* BsD1 = &Bs[(64 + wave * 16) * 32];

    floatx4 acc[4][4];
    for (int i = 0; i < 4; i++)
        for (int j = 0; j < 4; j++)
            acc[i][j] = floatx4{0.f, 0.f, 0.f, 0.f};

    for (int k0 = 0; k0 < K; k0 += 32) {
        __syncthreads();
        gl2lds16(Ag0 + k0, AsD0);
        gl2lds16(Ag1 + k0, AsD1);
        gl2lds16(Wg0 + k0, BsD0);
        gl2lds16(Wg1 + k0, BsD1);
        __syncthreads();

        bf16x8 af[4], bfr[4];
        for (int mi = 0; mi < 4; mi++)
            af[mi] = *(const bf16x8*)&As[(wm * 64 + mi * 16 + l16) * 32 + quad * 8];
        for (int ni = 0; ni < 4; ni++)
            bfr[ni] = *(const bf16x8*)&Bs[(wn * 64 + ni * 16 + l16) * 32 + quad * 8];
        for (int mi = 0; mi < 4; mi++)
            for (int ni = 0; ni < 4; ni++)
                acc[mi][ni] = __builtin_amdgcn_mfma_f32_16x16x32_bf16(
                    af[mi], bfr[ni], acc[mi][ni], 0, 0, 0);
    }

    for (int ni = 0; ni < 4; ni++) {
        const int n = n0 + wn * 64 + ni * 16 + l16;
        const float bv2 = bias[n];
        for (int mi = 0; mi < 4; mi++)
            for (int vv = 0; vv < 4; vv++) {
                const int m = m0 + wm * 64 + mi * 16 + quad * 4 + vv;
                outv[(size_t)m * N + n] = acc[mi][ni][vv] + bv2;
            }
    }
}

// ---------------- flash attention: 4 waves x 32 q-rows ----------------
// grid = B*H*(T/128) = 512 blocks, 256 thr. K/V 64-key LDS tiles shared by
// 4 waves, register-prefetched. P round-trip uses key-permuted columns
// (j = c + key16*4) so each lane stores 4 contiguous bf16 -> ds_write_b64;
// Vpt rows are pre-permuted identically by qkv_gemm, so PV is unchanged.
__global__ __launch_bounds__(256) void attn_kernel(
    const u16* __restrict__ Qp, const u16* __restrict__ Kp,
    const u16* __restrict__ Vpt, const int* __restrict__ mask,
    u16* __restrict__ Xa)
{
    constexpr int LDK = 72, LDP = 72;   // 144B rows: 16B-aligned, <=2-way banks
    __shared__ __align__(16) u16 Ks[64 * LDK];     // [key][dk]
    __shared__ __align__(16) u16 Vs[64 * LDK];     // [dk][key_perm]
    __shared__ __align__(16) __bf16 Pl[4][32][LDP];
    const int tid  = threadIdx.x;
    const int wave = tid >> 6, lane = tid & 63;
    const int quad = lane >> 4, l16 = lane & 15;
    const int bid = blockIdx.x;
    const int qt = bid & 15, bh = bid >> 4;
    const int b = bh >> 4, h = bh & 15;
    const int qbase = qt * 128 + wave * 32;

    const u16* Qb = Qp + (size_t)bh * TT * DKK;
    const u16* Kb = Kp + (size_t)bh * TT * DKK;
    const u16* Vb = Vpt + (size_t)bh * DKK * TT;
    const int* mk = mask + b * TT;

    const int srow = tid >> 3, scol = (tid & 7) * 8;

    bf16x8 qf[2][2];
    for (int mb = 0; mb < 2; mb++) {
        qf[mb][0] = *(const bf16x8*)&Qb[(size_t)(qbase + mb * 16 + l16) * DKK + quad * 8];
        qf[mb][1] = *(const bf16x8*)&Qb[(size_t)(qbase + mb * 16 + l16) * DKK + 32 + quad * 8];
    }

    floatx4 o[2][4];
    float rsum[2][4];
    for (int mb = 0; mb < 2; mb++)
        for (int i = 0; i < 4; i++) {
            o[mb][i] = floatx4{0.f, 0.f, 0.f, 0.f};
            rsum[mb][i] = 0.f;
        }

    uint4 kr0 = *(const uint4*)&Kb[(size_t)srow * DKK + scol];
    uint4 kr1 = *(const uint4*)&Kb[(size_t)(32 + srow) * DKK + scol];
    uint4 vr0 = *(const uint4*)&Vb[(size_t)srow * TT + scol];
    uint4 vr1 = *(const uint4*)&Vb[(size_t)(32 + srow) * TT + scol];

    for (int ti = 0; ti < TT / 64; ti++) {
        const int k0 = ti * 64;
        __syncthreads();
        *(uint4*)&Ks[srow * LDK + scol] = kr0;
        *(uint4*)&Ks[(32 + srow) * LDK + scol] = kr1;
        *(uint4*)&Vs[srow * LDK + scol] = vr0;
        *(uint4*)&Vs[(32 + srow) * LDK + scol] = vr1;
        __syncthreads();
        if (ti + 1 < TT / 64) {
            kr0 = *(const uint4*)&Kb[(size_t)(k0 + 64 + srow) * DKK + scol];
            kr1 = *(const uint4*)&Kb[(size_t)(k0 + 96 + srow) * DKK + scol];
            vr0 = *(const uint4*)&Vb[(size_t)srow * TT + k0 + 64 + scol];
            vr1 = *(const uint4*)&Vb[(size_t)(32 + srow) * TT + k0 + 64 + scol];
        }

        const int mv0 = mk[k0 + l16];
        const int mv1 = mk[k0 + 16 + l16];
        const int mv2 = mk[k0 + 32 + l16];
        const int mv3 = mk[k0 + 48 + l16];
        if (!__any(mv0 | mv1 | mv2 | mv3)) continue;   // block-uniform
        const float mf[4] = { mv0 ? 1.f : 0.f, mv1 ? 1.f : 0.f,
                              mv2 ? 1.f : 0.f, mv3 ? 1.f : 0.f };

        bf16x8 kf[4][2];
        for (int c = 0; c < 4; c++) {
            kf[c][0] = *(const bf16x8*)&Ks[(c * 16 + l16) * LDK + quad * 8];
            kf[c][1] = *(const bf16x8*)&Ks[(c * 16 + l16) * LDK + 32 + quad * 8];
        }

        for (int mb = 0; mb < 2; mb++) {
            floatx4 s[4];
            for (int c = 0; c < 4; c++) s[c] = floatx4{0.f, 0.f, 0.f, 0.f};
            for (int c = 0; c < 4; c++) {
                s[c] = __builtin_amdgcn_mfma_f32_16x16x32_bf16(qf[mb][0], kf[c][0], s[c], 0, 0, 0);
                s[c] = __builtin_amdgcn_mfma_f32_16x16x32_bf16(qf[mb][1], kf[c][1], s[c], 0, 0, 0);
            }
            float p[4][4];
            for (int c = 0; c < 4; c++)
                for (int v = 0; v < 4; v++) {
                    p[c][v] = __expf(s[c][v]) * mf[c];   // scale pre-folded into Q
                    rsum[mb][v] += p[c][v];
                }
            // packed P store: cols j = c + l16*4 contiguous -> one b64 per v
            for (int v = 0; v < 4; v++) {
                bf16x4 pv = { (__bf16)p[0][v], (__bf16)p[1][v],
                              (__bf16)p[2][v], (__bf16)p[3][v] };
                *(bf16x4*)&Pl[wave][mb * 16 + quad * 4 + v][l16 * 4] = pv;
            }
        }
        __asm__ volatile("" ::: "memory");
        bf16x8 pf[2][2];
        for (int mb = 0; mb < 2; mb++) {
            pf[mb][0] = *(const bf16x8*)&Pl[wave][mb * 16 + l16][quad * 8];
            pf[mb][1] = *(const bf16x8*)&Pl[wave][mb * 16 + l16][32 + quad * 8];
        }
        __asm__ volatile("" ::: "memory");

        for (int nb = 0; nb < 4; nb++) {
            const bf16x8 vf0 = *(const bf16x8*)&Vs[(nb * 16 + l16) * LDK + quad * 8];
            const bf16x8 vf1 = *(const bf16x8*)&Vs[(nb * 16 + l16) * LDK + 32 + quad * 8];
            o[0][nb] = __builtin_amdgcn_mfma_f32_16x16x32_bf16(pf[0][0], vf0, o[0][nb], 0, 0, 0);
            o[0][nb] = __builtin_amdgcn_mfma_f32_16x16x32_bf16(pf[0][1], vf1, o[0][nb], 0, 0, 0);
            o[1][nb] = __builtin_amdgcn_mfma_f32_16x16x32_bf16(pf[1][0], vf0, o[1][nb], 0, 0, 0);
            o[1][nb] = __builtin_amdgcn_mfma_f32_16x16x32_bf16(pf[1][1], vf1, o[1][nb], 0, 0, 0);
        }
    }

    for (int off = 1; off < 16; off <<= 1)
        for (int mb = 0; mb < 2; mb++)
            for (int v = 0; v < 4; v++)
                rsum[mb][v] += __shfl_xor(rsum[mb][v], off, 64);

    for (int mb = 0; mb < 2; mb++) {
        float inv[4];
        for (int v = 0; v < 4; v++) inv[v] = 1.0f / rsum[mb][v];
        for (int nb = 0; nb < 4; nb++)
            for (int v = 0; v < 4; v++) {
                const int t = qbase + mb * 16 + quad * 4 + v;
                Xa[((size_t)b * TT + t) * DD + h * DKK + nb * 16 + l16] =
                    f2bf(o[mb][nb][v] * inv[v]);
            }
    }
}

extern "C" void kernel_launch(void* const* d_in, const int* in_sizes, int n_in,
                              void* d_out, int out_size, void* d_ws, size_t ws_size,
                              hipStream_t stream) {
    const float* q    = (const float*)d_in[0];
    const float* k    = (const float*)d_in[1];
    const float* v    = (const float*)d_in[2];
    const int*   mask = (const int*)d_in[3];
    const float* Wq   = (const float*)d_in[4];
    const float* bq   = (const float*)d_in[5];
    const float* Wk   = (const float*)d_in[6];
    const float* bk   = (const float*)d_in[7];
    const float* Wv   = (const float*)d_in[8];
    const float* bv   = (const float*)d_in[9];
    const float* Wo   = (const float*)d_in[10];
    const float* bo   = (const float*)d_in[11];

    u16* Qc  = (u16*)d_ws;
    u16* Kc  = Qc + (size_t)ACT;
    u16* Vc  = Kc + (size_t)ACT;
    u16* Wqc = Vc + (size_t)ACT;
    u16* Wkc = Wqc + (size_t)WTE;
    u16* Wvc = Wkc + (size_t)WTE;
    u16* Woc = Wvc + (size_t)WTE;
    u16* Qp  = Woc + (size_t)WTE;
    u16* Kp  = Qp + (size_t)ACT;
    u16* Vpt = Kp + (size_t)ACT;
    u16* Xa  = Vpt + (size_t)ACT;

    CvtArgs ca;
    ca.src[0] = q;  ca.dst[0] = Qc;
    ca.src[1] = k;  ca.dst[1] = Kc;
    ca.src[2] = v;  ca.dst[2] = Vc;
    ca.src[3] = Wq; ca.dst[3] = Wqc;
    ca.src[4] = Wk; ca.dst[4] = Wkc;
    ca.src[5] = Wv; ca.dst[5] = Wvc;
    ca.src[6] = Wo; ca.dst[6] = Woc;
    convert_bf16<<<1024, 256, 0, stream>>>(ca);

    qkv_gemm<<<dim3(DD / 128, (BB * TT) / 128, 3), 256, 0, stream>>>(
        Qc, Kc, Vc, Wqc, Wkc, Wvc, bq, bk, bv, Qp);

    attn_kernel<<<dim3(BB * HH * (TT / 128)), 256, 0, stream>>>(Qp, Kp, Vpt, mask, Xa);

    out_gemm<<<dim3(DD / 128, (BB * TT) / 128), 256, 0, stream>>>(Xa, Woc, bo, (float*)d_out);
}

// Round 9
// 255.658 us; speedup vs baseline: 1.0226x; 1.0226x over previous
//
#include <hip/hip_runtime.h>

typedef unsigned short u16;
typedef unsigned int u32;
typedef __bf16 bf16x8 __attribute__((ext_vector_type(8)));
typedef __bf16 bf16x4 __attribute__((ext_vector_type(4)));
typedef float floatx4 __attribute__((ext_vector_type(4)));

#define BB 2
#define TT 2048
#define DD 1024
#define HH 16
#define DKK 64
#define ACT (BB * TT * DD)      // 4194304 elements
#define WTE (DD * DD)           // 1048576 elements
#define BHT (BB * HH * TT)      // 65536 rows

__device__ inline u16 f2bf(float f) {
    union { float f; u32 u; } c; c.f = f;
    u32 r = (c.u + 0x7fffu + ((c.u >> 16) & 1u)) >> 16;
    return (u16)r;
}
__device__ inline u32 pack2bf(float a, float b) {
    return (u32)f2bf(a) | ((u32)f2bf(b) << 16);
}

// async global->LDS, 16B per lane; LDS dest = wave-uniform base + lane*16
typedef __attribute__((address_space(1))) const u32 gas_u32;
typedef __attribute__((address_space(3))) u32 las_u32;
__device__ __forceinline__ void gl2lds16(const u16* g, u16* l) {
    __builtin_amdgcn_global_load_lds((gas_u32*)g, (las_u32*)l, 16, 0, 0);
}

// ---------------- fp32 -> bf16 convert pass ----------------
struct CvtArgs { const float* src[7]; u16* dst[7]; };
__global__ __launch_bounds__(256) void convert_bf16(CvtArgs a) {
    int bid = blockIdx.x, t, local;
    if (bid < 768) { t = bid >> 8; local = bid & 255; }
    else { int r = bid - 768; t = 3 + (r >> 6); local = r & 63; }
    const float* s = a.src[t];
    u16* d = a.dst[t];
    const int base = local * 16384;
    for (int i = 0; i < 8; i++) {
        const int idx = base + i * 2048 + threadIdx.x * 8;
        float4 x0 = *(const float4*)(s + idx);
        float4 x1 = *(const float4*)(s + idx + 4);
        uint4 p;
        p.x = pack2bf(x0.x, x0.y); p.y = pack2bf(x0.z, x0.w);
        p.z = pack2bf(x1.x, x1.y); p.w = pack2bf(x1.z, x1.w);
        *(uint4*)(d + idx) = p;
    }
}

// ---------------- fused QKV projection, BK=64 (two 32-col subtiles) --------
// z=0: Q*0.125 -> ws[b][h][t][dk]   z=1: K -> same
// z=2: V -> ws[b][h][dk][t_perm] (keys permuted: j = c + key16*4)
__global__ __launch_bounds__(256) void qkv_gemm(
    const u16* __restrict__ Qc, const u16* __restrict__ Kc,
    const u16* __restrict__ Vc,
    const u16* __restrict__ Wqc, const u16* __restrict__ Wkc,
    const u16* __restrict__ Wvc,
    const float* __restrict__ bq, const float* __restrict__ bk,
    const float* __restrict__ bv,
    u16* __restrict__ ws)
{
    __shared__ __align__(16) u16 As[2 * 128 * 32];   // [kh][row][32]
    __shared__ __align__(16) u16 Bs[2 * 128 * 32];
    const int z = blockIdx.z;
    const u16* A = (z == 0) ? Qc : (z == 1) ? Kc : Vc;
    const u16* W = (z == 0) ? Wqc : (z == 1) ? Wkc : Wvc;
    const float* bias = (z == 0) ? bq : (z == 1) ? bk : bv;
    u16* out = ws + (size_t)z * (size_t)BB * HH * TT * DKK;

    const int tid  = threadIdx.x;
    const int wave = tid >> 6, lane = tid & 63;
    const int quad = lane >> 4, l16 = lane & 15;
    const int wm = wave & 1, wn = wave >> 1;
    const int m0 = blockIdx.y * 128, n0 = blockIdx.x * 128;
    const int K = DD;

    // staging lane map: row = lane>>2 (16 rows/call), 16B unit = lane&3
    const int lrow = lane >> 2, lcol = (lane & 3) * 8;
    // global row-base pointers for the two 64-row halves
    const u16* Ag[2] = { A + (size_t)(m0 + wave * 16 + lrow) * K + lcol,
                         A + (size_t)(m0 + 64 + wave * 16 + lrow) * K + lcol };
    const u16* Wg[2] = { W + (size_t)(n0 + wave * 16 + lrow) * K + lcol,
                         W + (size_t)(n0 + 64 + wave * 16 + lrow) * K + lcol };
    u16* AsD[2][2], *BsD[2][2];   // [kh][rowhalf]
    for (int kh = 0; kh < 2; kh++)
        for (int j = 0; j < 2; j++) {
            AsD[kh][j] = &As[kh * 4096 + (j * 64 + wave * 16) * 32];
            BsD[kh][j] = &Bs[kh * 4096 + (j * 64 + wave * 16) * 32];
        }

    floatx4 acc[4][4];
    for (int i = 0; i < 4; i++)
        for (int j = 0; j < 4; j++)
            acc[i][j] = floatx4{0.f, 0.f, 0.f, 0.f};

    for (int k0 = 0; k0 < K; k0 += 64) {
        __syncthreads();
        for (int kh = 0; kh < 2; kh++)
            for (int j = 0; j < 2; j++) {
                gl2lds16(Ag[j] + k0 + kh * 32, AsD[kh][j]);
                gl2lds16(Wg[j] + k0 + kh * 32, BsD[kh][j]);
            }
        __syncthreads();

        bf16x8 af[4][2], bfr[4][2];
        for (int kh = 0; kh < 2; kh++) {
            for (int mi = 0; mi < 4; mi++)
                af[mi][kh] = *(const bf16x8*)&As[kh * 4096 + (wm * 64 + mi * 16 + l16) * 32 + quad * 8];
            for (int ni = 0; ni < 4; ni++)
                bfr[ni][kh] = *(const bf16x8*)&Bs[kh * 4096 + (wn * 64 + ni * 16 + l16) * 32 + quad * 8];
        }
        for (int kh = 0; kh < 2; kh++)
            for (int mi = 0; mi < 4; mi++)
                for (int ni = 0; ni < 4; ni++)
                    acc[mi][ni] = __builtin_amdgcn_mfma_f32_16x16x32_bf16(
                        af[mi][kh], bfr[ni][kh], acc[mi][ni], 0, 0, 0);
    }

    for (int ni = 0; ni < 4; ni++) {
        const int n = n0 + wn * 64 + ni * 16 + l16;
        const float bv2 = bias[n];
        for (int mi = 0; mi < 4; mi++) {
            for (int vv = 0; vv < 4; vv++) {
                const int m = m0 + wm * 64 + mi * 16 + quad * 4 + vv;
                float val = acc[mi][ni][vv] + bv2;
                if (z == 0) val *= 0.125f;   // fold 1/sqrt(DK)
                const int b = m >> 11, t = m & 2047, h = n >> 6, dk = n & 63;
                if (z == 2) {
                    const int tp = (t & ~63) | ((t >> 4) & 3) | ((t & 15) << 2);
                    out[(((size_t)(b * HH + h)) * DKK + dk) * TT + tp] = f2bf(val);
                } else {
                    out[(((size_t)(b * HH + h)) * TT + t) * DKK + dk] = f2bf(val);
                }
            }
        }
    }
}

// ---------------- output projection, BK=64 ----------------
__global__ __launch_bounds__(256) void out_gemm(
    const u16* __restrict__ Av, const u16* __restrict__ Wv,
    const float* __restrict__ bias, float* __restrict__ outv)
{
    __shared__ __align__(16) u16 As[2 * 128 * 32];
    __shared__ __align__(16) u16 Bs[2 * 128 * 32];
    const int tid  = threadIdx.x;
    const int wave = tid >> 6, lane = tid & 63;
    const int quad = lane >> 4, l16 = lane & 15;
    const int wm = wave & 1, wn = wave >> 1;
    const int m0 = blockIdx.y * 128, n0 = blockIdx.x * 128;
    const int K = DD, N = DD;

    const int lrow = lane >> 2, lcol = (lane & 3) * 8;
    const u16* Ag[2] = { Av + (size_t)(m0 + wave * 16 + lrow) * K + lcol,
                         Av + (size_t)(m0 + 64 + wave * 16 + lrow) * K + lcol };
    const u16* Wg[2] = { Wv + (size_t)(n0 + wave * 16 + lrow) * K + lcol,
                         Wv + (size_t)(n0 + 64 + wave * 16 + lrow) * K + lcol };
    u16* AsD[2][2], *BsD[2][2];
    for (int kh = 0; kh < 2; kh++)
        for (int j = 0; j < 2; j++) {
            AsD[kh][j] = &As[kh * 4096 + (j * 64 + wave * 16) * 32];
            BsD[kh][j] = &Bs[kh * 4096 + (j * 64 + wave * 16) * 32];
        }

    floatx4 acc[4][4];
    for (int i = 0; i < 4; i++)
        for (int j = 0; j < 4; j++)
            acc[i][j] = floatx4{0.f, 0.f, 0.f, 0.f};

    for (int k0 = 0; k0 < K; k0 += 64) {
        __syncthreads();
        for (int kh = 0; kh < 2; kh++)
            for (int j = 0; j < 2; j++) {
                gl2lds16(Ag[j] + k0 + kh * 32, AsD[kh][j]);
                gl2lds16(Wg[j] + k0 + kh * 32, BsD[kh][j]);
            }
        __syncthreads();

        bf16x8 af[4][2], bfr[4][2];
        for (int kh = 0; kh < 2; kh++) {
            for (int mi = 0; mi < 4; mi++)
                af[mi][kh] = *(const bf16x8*)&As[kh * 4096 + (wm * 64 + mi * 16 + l16) * 32 + quad * 8];
            for (int ni = 0; ni < 4; ni++)
                bfr[ni][kh] = *(const bf16x8*)&Bs[kh * 4096 + (wn * 64 + ni * 16 + l16) * 32 + quad * 8];
        }
        for (int kh = 0; kh < 2; kh++)
            for (int mi = 0; mi < 4; mi++)
                for (int ni = 0; ni < 4; ni++)
                    acc[mi][ni] = __builtin_amdgcn_mfma_f32_16x16x32_bf16(
                        af[mi][kh], bfr[ni][kh], acc[mi][ni], 0, 0, 0);
    }

    for (int ni = 0; ni < 4; ni++) {
        const int n = n0 + wn * 64 + ni * 16 + l16;
        const float bv2 = bias[n];
        for (int mi = 0; mi < 4; mi++)
            for (int vv = 0; vv < 4; vv++) {
                const int m = m0 + wm * 64 + mi * 16 + quad * 4 + vv;
                outv[(size_t)m * N + n] = acc[mi][ni][vv] + bv2;
            }
    }
}

// ---------------- flash attention, split keys in 2 ----------------
// grid = (B*H*(T/128), 2): blockIdx.y = key half. No max-tracking, so split
// softmax combines LINEARLY: out = (o0+o1)/(rs0+rs1) -> combine kernel.
// 1024 blocks -> 4 blocks/CU, 16 waves/CU (2x latency hiding vs r8).
__global__ __launch_bounds__(256) void attn_kernel(
    const u16* __restrict__ Qp, const u16* __restrict__ Kp,
    const u16* __restrict__ Vpt, const int* __restrict__ mask,
    u16* __restrict__ Opart, float* __restrict__ Rpart)
{
    constexpr int LDK = 72, LDP = 72;
    __shared__ __align__(16) u16 Ks[64 * LDK];     // [key][dk]
    __shared__ __align__(16) u16 Vs[64 * LDK];     // [dk][key_perm]
    __shared__ __align__(16) __bf16 Pl[4][32][LDP];
    const int tid  = threadIdx.x;
    const int wave = tid >> 6, lane = tid & 63;
    const int quad = lane >> 4, l16 = lane & 15;
    const int bid = blockIdx.x;
    const int half = blockIdx.y;
    const int qt = bid & 15, bh = bid >> 4;
    const int b = bh >> 4;
    const int qbase = qt * 128 + wave * 32;
    const int kstart = half * (TT / 2);

    const u16* Qb = Qp + (size_t)bh * TT * DKK;
    const u16* Kb = Kp + (size_t)bh * TT * DKK;
    const u16* Vb = Vpt + (size_t)bh * DKK * TT;
    const int* mk = mask + b * TT;

    const int srow = tid >> 3, scol = (tid & 7) * 8;

    bf16x8 qf[2][2];
    for (int mb = 0; mb < 2; mb++) {
        qf[mb][0] = *(const bf16x8*)&Qb[(size_t)(qbase + mb * 16 + l16) * DKK + quad * 8];
        qf[mb][1] = *(const bf16x8*)&Qb[(size_t)(qbase + mb * 16 + l16) * DKK + 32 + quad * 8];
    }

    floatx4 o[2][4];
    float rsum[2][4];
    for (int mb = 0; mb < 2; mb++)
        for (int i = 0; i < 4; i++) {
            o[mb][i] = floatx4{0.f, 0.f, 0.f, 0.f};
            rsum[mb][i] = 0.f;
        }

    uint4 kr0 = *(const uint4*)&Kb[(size_t)(kstart + srow) * DKK + scol];
    uint4 kr1 = *(const uint4*)&Kb[(size_t)(kstart + 32 + srow) * DKK + scol];
    uint4 vr0 = *(const uint4*)&Vb[(size_t)srow * TT + kstart + scol];
    uint4 vr1 = *(const uint4*)&Vb[(size_t)(32 + srow) * TT + kstart + scol];

    for (int ti = 0; ti < TT / 128; ti++) {
        const int k0 = kstart + ti * 64;
        __syncthreads();
        *(uint4*)&Ks[srow * LDK + scol] = kr0;
        *(uint4*)&Ks[(32 + srow) * LDK + scol] = kr1;
        *(uint4*)&Vs[srow * LDK + scol] = vr0;
        *(uint4*)&Vs[(32 + srow) * LDK + scol] = vr1;
        __syncthreads();
        if (ti + 1 < TT / 128) {
            kr0 = *(const uint4*)&Kb[(size_t)(k0 + 64 + srow) * DKK + scol];
            kr1 = *(const uint4*)&Kb[(size_t)(k0 + 96 + srow) * DKK + scol];
            vr0 = *(const uint4*)&Vb[(size_t)srow * TT + k0 + 64 + scol];
            vr1 = *(const uint4*)&Vb[(size_t)(32 + srow) * TT + k0 + 64 + scol];
        }

        const int mv0 = mk[k0 + l16];
        const int mv1 = mk[k0 + 16 + l16];
        const int mv2 = mk[k0 + 32 + l16];
        const int mv3 = mk[k0 + 48 + l16];
        if (!__any(mv0 | mv1 | mv2 | mv3)) continue;   // block-uniform
        const float mf[4] = { mv0 ? 1.f : 0.f, mv1 ? 1.f : 0.f,
                              mv2 ? 1.f : 0.f, mv3 ? 1.f : 0.f };

        bf16x8 kf[4][2];
        for (int c = 0; c < 4; c++) {
            kf[c][0] = *(const bf16x8*)&Ks[(c * 16 + l16) * LDK + quad * 8];
            kf[c][1] = *(const bf16x8*)&Ks[(c * 16 + l16) * LDK + 32 + quad * 8];
        }

        for (int mb = 0; mb < 2; mb++) {
            floatx4 s[4];
            for (int c = 0; c < 4; c++) s[c] = floatx4{0.f, 0.f, 0.f, 0.f};
            for (int c = 0; c < 4; c++) {
                s[c] = __builtin_amdgcn_mfma_f32_16x16x32_bf16(qf[mb][0], kf[c][0], s[c], 0, 0, 0);
                s[c] = __builtin_amdgcn_mfma_f32_16x16x32_bf16(qf[mb][1], kf[c][1], s[c], 0, 0, 0);
            }
            float p[4][4];
            for (int c = 0; c < 4; c++)
                for (int v = 0; v < 4; v++) {
                    p[c][v] = __expf(s[c][v]) * mf[c];   // scale folded into Q
                    rsum[mb][v] += p[c][v];
                }
            for (int v = 0; v < 4; v++) {
                bf16x4 pv = { (__bf16)p[0][v], (__bf16)p[1][v],
                              (__bf16)p[2][v], (__bf16)p[3][v] };
                *(bf16x4*)&Pl[wave][mb * 16 + quad * 4 + v][l16 * 4] = pv;
            }
        }
        __asm__ volatile("" ::: "memory");
        bf16x8 pf[2][2];
        for (int mb = 0; mb < 2; mb++) {
            pf[mb][0] = *(const bf16x8*)&Pl[wave][mb * 16 + l16][quad * 8];
            pf[mb][1] = *(const bf16x8*)&Pl[wave][mb * 16 + l16][32 + quad * 8];
        }
        __asm__ volatile("" ::: "memory");

        for (int nb = 0; nb < 4; nb++) {
            const bf16x8 vf0 = *(const bf16x8*)&Vs[(nb * 16 + l16) * LDK + quad * 8];
            const bf16x8 vf1 = *(const bf16x8*)&Vs[(nb * 16 + l16) * LDK + 32 + quad * 8];
            o[0][nb] = __builtin_amdgcn_mfma_f32_16x16x32_bf16(pf[0][0], vf0, o[0][nb], 0, 0, 0);
            o[0][nb] = __builtin_amdgcn_mfma_f32_16x16x32_bf16(pf[0][1], vf1, o[0][nb], 0, 0, 0);
            o[1][nb] = __builtin_amdgcn_mfma_f32_16x16x32_bf16(pf[1][0], vf0, o[1][nb], 0, 0, 0);
            o[1][nb] = __builtin_amdgcn_mfma_f32_16x16x32_bf16(pf[1][1], vf1, o[1][nb], 0, 0, 0);
        }
    }

    for (int off = 1; off < 16; off <<= 1)
        for (int mb = 0; mb < 2; mb++)
            for (int v = 0; v < 4; v++)
                rsum[mb][v] += __shfl_xor(rsum[mb][v], off, 64);

    // store partials: o (bf16) and rsum (fp32, one lane per row)
    u16* Ob = Opart + (size_t)half * BHT * DKK + (size_t)bh * TT * DKK;
    float* Rb = Rpart + (size_t)half * BHT + (size_t)bh * TT;
    for (int mb = 0; mb < 2; mb++) {
        for (int nb = 0; nb < 4; nb++)
            for (int v = 0; v < 4; v++) {
                const int r = qbase + mb * 16 + quad * 4 + v;
                Ob[(size_t)r * DKK + nb * 16 + l16] = f2bf(o[mb][nb][v]);
            }
        if (l16 == 0)
            for (int v = 0; v < 4; v++)
                Rb[qbase + mb * 16 + quad * 4 + v] = rsum[mb][v];
    }
}

// ---------------- combine split-K partials -> Xa ----------------
__global__ __launch_bounds__(256) void attn_combine(
    const u16* __restrict__ Opart, const float* __restrict__ Rpart,
    u16* __restrict__ Xa)
{
    const int g = blockIdx.x * 256 + threadIdx.x;   // 0 .. BHT*8-1
    const int row = g >> 3, cg = g & 7;
    const int bh = row >> 11, t = row & 2047;
    const int b = bh >> 4, h = bh & 15;
    const bf16x8 o0 = *(const bf16x8*)&Opart[(size_t)row * DKK + cg * 8];
    const bf16x8 o1 = *(const bf16x8*)&Opart[(size_t)BHT * DKK + (size_t)row * DKK + cg * 8];
    const float inv = 1.0f / (Rpart[row] + Rpart[BHT + row]);
    float r[8];
    for (int i = 0; i < 8; i++)
        r[i] = ((float)o0[i] + (float)o1[i]) * inv;
    uint4 p;
    p.x = pack2bf(r[0], r[1]); p.y = pack2bf(r[2], r[3]);
    p.z = pack2bf(r[4], r[5]); p.w = pack2bf(r[6], r[7]);
    *(uint4*)&Xa[(((size_t)b * TT + t) * DD) + h * DKK + cg * 8] = p;
}

extern "C" void kernel_launch(void* const* d_in, const int* in_sizes, int n_in,
                              void* d_out, int out_size, void* d_ws, size_t ws_size,
                              hipStream_t stream) {
    const float* q    = (const float*)d_in[0];
    const float* k    = (const float*)d_in[1];
    const float* v    = (const float*)d_in[2];
    const int*   mask = (const int*)d_in[3];
    const float* Wq   = (const float*)d_in[4];
    const float* bq   = (const float*)d_in[5];
    const float* Wk   = (const float*)d_in[6];
    const float* bk   = (const float*)d_in[7];
    const float* Wv   = (const float*)d_in[8];
    const float* bv   = (const float*)d_in[9];
    const float* Wo   = (const float*)d_in[10];
    const float* bo   = (const float*)d_in[11];

    // ws: Qc|Kc|Vc (dead after qkv_gemm -> reused for Opart/Rpart) |
    //     Wqc..Woc | Qp|Kp|Vpt|Xa
    u16* Qc  = (u16*)d_ws;
    u16* Kc  = Qc + (size_t)ACT;
    u16* Vc  = Kc + (size_t)ACT;
    u16* Wqc = Vc + (size_t)ACT;
    u16* Wkc = Wqc + (size_t)WTE;
    u16* Wvc = Wkc + (size_t)WTE;
    u16* Woc = Wvc + (size_t)WTE;
    u16* Qp  = Woc + (size_t)WTE;
    u16* Kp  = Qp + (size_t)ACT;
    u16* Vpt = Kp + (size_t)ACT;
    u16* Xa  = Vpt + (size_t)ACT;

    u16*   Opart = Qc;            // 2 * BHT * 64 u16 = 16 MB (Qc+Kc region)
    float* Rpart = (float*)Vc;    // 2 * BHT fp32 = 512 KB

    CvtArgs ca;
    ca.src[0] = q;  ca.dst[0] = Qc;
    ca.src[1] = k;  ca.dst[1] = Kc;
    ca.src[2] = v;  ca.dst[2] = Vc;
    ca.src[3] = Wq; ca.dst[3] = Wqc;
    ca.src[4] = Wk; ca.dst[4] = Wkc;
    ca.src[5] = Wv; ca.dst[5] = Wvc;
    ca.src[6] = Wo; ca.dst[6] = Woc;
    convert_bf16<<<1024, 256, 0, stream>>>(ca);

    qkv_gemm<<<dim3(DD / 128, (BB * TT) / 128, 3), 256, 0, stream>>>(
        Qc, Kc, Vc, Wqc, Wkc, Wvc, bq, bk, bv, Qp);

    attn_kernel<<<dim3(BB * HH * (TT / 128), 2), 256, 0, stream>>>(
        Qp, Kp, Vpt, mask, Opart, Rpart);

    attn_combine<<<(BHT * 8) / 256, 256, 0, stream>>>(Opart, Rpart, Xa);

    out_gemm<<<dim3(DD / 128, (BB * TT) / 128), 256, 0, stream>>>(Xa, Woc, bo, (float*)d_out);
}